// Round 2
// baseline (336.539 us; speedup 1.0000x reference)
//
#include <hip/hip_runtime.h>

#define N_NODES  100000
#define M_PAD    100096   // 782 * 128 (and 3128 * 32)
#define N_EDGES  1600000
#define N_GRAPHS 512
#define IN_DIM   128
#define HID_DIM  256
#define OUT_DIM  128

#define NB       782      // buckets of 128 nodes
#define BCAP     3072     // mean 2048, +22 sigma headroom
#define CHUNK    2048     // edges per bucket_v2 block
#define BKB      ((N_EDGES + CHUNK - 1) / CHUNK)   // 782

typedef __bf16 bf16x8 __attribute__((ext_vector_type(8)));
typedef __bf16 bf16x4 __attribute__((ext_vector_type(4)));
typedef __bf16 bf16x2 __attribute__((ext_vector_type(2)));
typedef float  f32x4  __attribute__((ext_vector_type(4)));

// ---- packed weight buffer layout (frag-ordered, LINEAR group stream) ----
// 32 groups x 8 frags x 512 elems: L1 groups 0-7, L2 8-23, L3 24-31.
#define WP_L2_BASE 32768
#define WP_L3_BASE 98304
#define WP_TOTAL   131072

// ---------------- fused init ----------------
#define R_X    (N_NODES * IN_DIM / 4)
#define R_APAD ((M_PAD - N_NODES) * IN_DIM / 4)
#define R_WP   WP_TOTAL
#define R_OUT  (N_GRAPHS * OUT_DIM / 4)
#define R_CUR  NB
#define R_TOTAL (R_X + R_APAD + R_WP + R_OUT + R_CUR)

__global__ __launch_bounds__(256) void init_kernel(const float* __restrict__ x,
                                                   const float* __restrict__ W1,
                                                   const float* __restrict__ W2,
                                                   const float* __restrict__ Wo,
                                                   __bf16* __restrict__ xb,
                                                   __bf16* __restrict__ Apad,
                                                   __bf16* __restrict__ Wp,
                                                   float* __restrict__ outbuf,
                                                   int* __restrict__ gcursor) {
    long long i = (long long)blockIdx.x * blockDim.x + threadIdx.x;
    if (i < R_X) {
        float4 v = ((const float4*)x)[i];
        bf16x4 h;
        h.x = (__bf16)v.x; h.y = (__bf16)v.y; h.z = (__bf16)v.z; h.w = (__bf16)v.w;
        ((bf16x4*)xb)[i] = h;
        return;
    }
    i -= R_X;
    if (i < R_APAD) {
        bf16x4 z; z.x = (__bf16)0.f; z.y = (__bf16)0.f; z.z = (__bf16)0.f; z.w = (__bf16)0.f;
        ((bf16x4*)Apad)[i] = z;
        return;
    }
    i -= R_APAD;
    if (i < R_WP) {
        int idx = (int)i;
        const float* src;
        int K, Nn, base;
        if (idx < WP_L2_BASE)      { src = W1; K = 128; Nn = 256; base = 0; }
        else if (idx < WP_L3_BASE) { src = W2; K = 256; Nn = 256; base = WP_L2_BASE; }
        else                       { src = Wo; K = 256; Nn = 128; base = WP_L3_BASE; }
        int r0 = idx - base;
        int slabElems = 32 * K;          // power of two
        int j = r0 / slabElems;
        int r = r0 % slabElems;
        int KS = K / 32;
        int p = r >> 9;
        int lane = (r >> 3) & 63;
        int e = r & 7;
        int s = p % KS, t = p / KS;
        int quad = lane >> 4, l16 = lane & 15;
        int n = j * 32 + t * 16 + l16;
        int k = s * 32 + quad * 8 + e;
        Wp[idx] = (__bf16)src[(size_t)k * Nn + n];
        return;
    }
    i -= R_WP;
    if (i < R_OUT) {
        ((float4*)outbuf)[i] = make_float4(0.f, 0.f, 0.f, 0.f);
        return;
    }
    i -= R_OUT;
    if (i < R_CUR) gcursor[i] = 0;
}

// ---------------- bucket_v2: LDS-staged edge binning ----------------
__global__ __launch_bounds__(256) void bucket_v2_kernel(const int* __restrict__ ei,
                                                        int* __restrict__ gcursor,
                                                        unsigned* __restrict__ pairBuf) {
    __shared__ int lcnt[NB];
    __shared__ int lbase[NB];
    const int tid = threadIdx.x;
    const int e0 = blockIdx.x * CHUNK;

    for (int b = tid; b < NB; b += 256) lcnt[b] = 0;
    __syncthreads();

    for (int i = tid; i < CHUNK; i += 256) {
        int e = e0 + i;
        if (e < N_EDGES) atomicAdd(&lcnt[ei[N_EDGES + e] >> 7], 1);
    }
    __syncthreads();

    for (int b = tid; b < NB; b += 256) {
        int c = lcnt[b];
        lbase[b] = c ? atomicAdd(&gcursor[b], c) : 0;
        lcnt[b] = 0;
    }
    __syncthreads();

    for (int i = tid; i < CHUNK; i += 256) {
        int e = e0 + i;
        if (e < N_EDGES) {
            int s = ei[e];
            int d = ei[N_EDGES + e];
            int b = d >> 7;
            int pos = lbase[b] + atomicAdd(&lcnt[b], 1);
            if (pos < BCAP)
                pairBuf[(size_t)b * BCAP + pos] = (unsigned)s | ((unsigned)(d & 127) << 17);
        }
    }
}

// ---------------- passB: per-bucket CSR build (bucket-strided) ----------------
__global__ __launch_bounds__(256) void passB_kernel(const unsigned* __restrict__ pairBuf,
                                                    const int* __restrict__ gcursor,
                                                    int* __restrict__ nbr,
                                                    int* __restrict__ offsets,
                                                    int* __restrict__ deg) {
    __shared__ int lcnt[128];
    __shared__ int loffs[128];
    __shared__ int lcur[128];
    const int b = blockIdx.x;
    const int tid = threadIdx.x;
    const int node0 = b << 7;
    const int cnt = min(gcursor[b], BCAP);
    const int base = b * BCAP;
    const unsigned* pb = pairBuf + (size_t)b * BCAP;

    if (tid < 128) { lcnt[tid] = 0; lcur[tid] = 0; }
    __syncthreads();

    for (int i = tid; i < cnt; i += 256)
        atomicAdd(&lcnt[pb[i] >> 17], 1);
    __syncthreads();

    if (tid < 128) loffs[tid] = lcnt[tid];
    __syncthreads();
    for (int st = 1; st < 128; st <<= 1) {
        int add = (tid < 128 && tid >= st) ? loffs[tid - st] : 0;
        __syncthreads();
        if (tid < 128) loffs[tid] += add;
        __syncthreads();
    }
    int excl = 0;
    if (tid < 128) {
        excl = loffs[tid] - lcnt[tid];
        int node = node0 + tid;
        if (node < N_NODES) {
            deg[node] = lcnt[tid];
            offsets[node] = base + excl;
        }
    }
    __syncthreads();
    if (tid < 128) loffs[tid] = excl;
    __syncthreads();

    for (int i = tid; i < cnt; i += 256) {
        unsigned u = pb[i];
        int dl = u >> 17;
        int slot = atomicAdd(&lcur[dl], 1);
        nbr[base + loffs[dl] + slot] = (int)(u & 0x1FFFF);
    }
}

// ---------------- gather aggregate (at memory floor) ----------------
__global__ __launch_bounds__(256) void aggregate_kernel(const __bf16* __restrict__ xb,
                                                        const int* __restrict__ offsets,
                                                        const int* __restrict__ deg,
                                                        const int* __restrict__ nbr,
                                                        __bf16* __restrict__ A) {
    int v = blockIdx.x * 4 + (threadIdx.x >> 6);
    v = __builtin_amdgcn_readfirstlane(v);
    int lane = threadIdx.x & 63;
    if (v >= N_NODES) return;
    int off = offsets[v];
    int len = deg[v];
    const int c0 = lane * 2;
    bf16x2 self = *(const bf16x2*)(xb + (size_t)v * IN_DIM + c0);
    float ax = (float)self.x, ay = (float)self.y;

    int addr = off + lane;
    if (addr > NB * BCAP - 1) addr = NB * BCAP - 1;
    int myidx = nbr[addr];

    int lim = len < 64 ? len : 64;
    int j = 0;
    for (; j + 8 <= lim; j += 8) {
        int s0 = __shfl(myidx, j + 0, 64);
        int s1 = __shfl(myidx, j + 1, 64);
        int s2 = __shfl(myidx, j + 2, 64);
        int s3 = __shfl(myidx, j + 3, 64);
        int s4 = __shfl(myidx, j + 4, 64);
        int s5 = __shfl(myidx, j + 5, 64);
        int s6 = __shfl(myidx, j + 6, 64);
        int s7 = __shfl(myidx, j + 7, 64);
        bf16x2 v0 = *(const bf16x2*)(xb + (size_t)s0 * IN_DIM + c0);
        bf16x2 v1 = *(const bf16x2*)(xb + (size_t)s1 * IN_DIM + c0);
        bf16x2 v2 = *(const bf16x2*)(xb + (size_t)s2 * IN_DIM + c0);
        bf16x2 v3 = *(const bf16x2*)(xb + (size_t)s3 * IN_DIM + c0);
        bf16x2 v4 = *(const bf16x2*)(xb + (size_t)s4 * IN_DIM + c0);
        bf16x2 v5 = *(const bf16x2*)(xb + (size_t)s5 * IN_DIM + c0);
        bf16x2 v6 = *(const bf16x2*)(xb + (size_t)s6 * IN_DIM + c0);
        bf16x2 v7 = *(const bf16x2*)(xb + (size_t)s7 * IN_DIM + c0);
        ax += (float)v0.x + (float)v1.x + (float)v2.x + (float)v3.x
            + (float)v4.x + (float)v5.x + (float)v6.x + (float)v7.x;
        ay += (float)v0.y + (float)v1.y + (float)v2.y + (float)v3.y
            + (float)v4.y + (float)v5.y + (float)v6.y + (float)v7.y;
    }
    for (; j < lim; ++j) {
        int s = __shfl(myidx, j, 64);
        bf16x2 vv = *(const bf16x2*)(xb + (size_t)s * IN_DIM + c0);
        ax += (float)vv.x;
        ay += (float)vv.y;
    }
    for (; j < len; ++j) {
        int s = nbr[off + j];
        bf16x2 vv = *(const bf16x2*)(xb + (size_t)s * IN_DIM + c0);
        ax += (float)vv.x;
        ay += (float)vv.y;
    }
    bf16x2 h;
    h.x = (__bf16)ax;
    h.y = (__bf16)ay;
    *(bf16x2*)(A + (size_t)v * IN_DIM + c0) = h;
}

// ---------------- fused 3-layer MLP + pool ----------------
// v3: LDS-shared weight stream + 64-row waves.
// v2 post-mortem: rolled loops fixed I$ (110->72us) but MfmaUtil stuck at 14%.
// Remaining stall = per-WAVE weight stream from L2 (826 MB chip-wide, depth-1
// prefetch vs ~250cy L2 latency, L1 thrashed by 10 concurrent streams).
// v3: block = 2 waves x 64 rows (128 rows). Weight groups (8KB) staged ONCE
// per block into LDS dbuf (reg-staged: loads issued at group top, ds_write at
// group bottom -> HBM/L2 latency hides under ~400cy of MFMA). Each ds_read
// frag feeds 4 MFMAs (64 rows). LDS: H 64KB + WB 16KB = 80KB -> 2 blocks/CU.
// Per group/CU: LDS ~384cy vs MFMA 160cy/SIMD -> est 12-20us.
#define MLP_ROWS_W  64          // rows per wave
#define MLP_WAVES   2
#define MLP_ROWS_B  (MLP_ROWS_W * MLP_WAVES)   // 128

__device__ __forceinline__ void stage_issue(const __bf16* __restrict__ g, int wid, int lane,
                                            bf16x8* __restrict__ r) {
    const __bf16* p = g + wid * 2048 + lane * 8;
    #pragma unroll
    for (int c = 0; c < 4; ++c)
        r[c] = *(const bf16x8*)(p + c * 512);
}

__device__ __forceinline__ void stage_write(__bf16* __restrict__ lb, int wid, int lane,
                                            const bf16x8* __restrict__ r) {
    __bf16* p = lb + wid * 2048 + lane * 8;
    #pragma unroll
    for (int c = 0; c < 4; ++c)
        *(bf16x8*)(p + c * 512) = r[c];
}

__device__ __forceinline__ void read_frags(const __bf16* __restrict__ lb, int lane,
                                           bf16x8* __restrict__ f) {
    #pragma unroll
    for (int e = 0; e < 8; ++e)
        f[e] = *(const bf16x8*)(lb + (e * 64 + lane) * 8);
}

__device__ __forceinline__ void mfma_L1(const bf16x8 (&a)[4][8], const bf16x8* __restrict__ f,
                                        f32x4 (&acc)[4][2]) {
    #pragma unroll
    for (int p = 0; p < 8; ++p) {
        const int t = p >> 2, s = p & 3;
        #pragma unroll
        for (int i = 0; i < 4; ++i)
            acc[i][t] = __builtin_amdgcn_mfma_f32_16x16x32_bf16(a[i][s], f[p], acc[i][t], 0, 0, 0);
    }
}

__device__ __forceinline__ void mfma_K256(const bf16x8 (&a)[4][8], const bf16x8* __restrict__ f,
                                          f32x4 (&acc)[4][2], int t) {
    #pragma unroll
    for (int p = 0; p < 8; ++p)
        #pragma unroll
        for (int i = 0; i < 4; ++i)
            acc[i][t] = __builtin_amdgcn_mfma_f32_16x16x32_bf16(a[i][p], f[p], acc[i][t], 0, 0, 0);
}

__device__ __forceinline__ void store_H(__bf16* __restrict__ H, int j, int quad, int l16,
                                        const f32x4 (&acc)[4][2], float bt0, float bt1) {
    const int c7 = l16 & 7;
    const int ch = l16 >> 3;
    #pragma unroll
    for (int i = 0; i < 4; ++i)
        #pragma unroll
        for (int t = 0; t < 2; ++t) {
            const float bb = t ? bt1 : bt0;
            #pragma unroll
            for (int rr = 0; rr < 4; ++rr) {
                int row = i * 16 + quad * 4 + rr;
                int cidx = (j * 4 + t * 2 + ch + row) & 31;
                float v = fmaxf(acc[i][t][rr] + bb, 0.f);
                H[row * 256 + cidx * 8 + c7] = (__bf16)v;
            }
        }
}

__global__ __launch_bounds__(128, 1) void mlp_fused(const __bf16* __restrict__ A,
                                                    const __bf16* __restrict__ Wp,
                                                    const float* __restrict__ b1,
                                                    const float* __restrict__ b2,
                                                    const float* __restrict__ bo,
                                                    float* __restrict__ out,
                                                    const int* __restrict__ batch) {
    __shared__ __align__(16) __bf16 H[MLP_ROWS_B * 256];   // 64 KB
    __shared__ __align__(16) __bf16 WB[2][4096];           // 2 x 8 KB dbuf

    const int tid  = threadIdx.x;
    const int wid  = tid >> 6;
    const int lane = tid & 63;
    const int quad = lane >> 4, l16 = lane & 15;
    __bf16* Hw = H + wid * MLP_ROWS_W * 256;

    const size_t mblk = (size_t)blockIdx.x * MLP_ROWS_B + wid * MLP_ROWS_W;
    const int r0g = (int)mblk;
    int gfirst = (r0g < N_NODES) ? batch[r0g] : -2;
    int glast  = (r0g + 63 < N_NODES) ? batch[r0g + 63] : -1;

    bf16x8 a[4][8];
    bf16x8 f[8];
    bf16x8 st[4];

    // ---- prologue: stage group 0 + layer-1 A-frags ----
    stage_issue(Wp, wid, lane, st);
    #pragma unroll
    for (int i = 0; i < 4; ++i)
        #pragma unroll
        for (int s = 0; s < 4; ++s)
            a[i][s] = *(const bf16x8*)(A + (mblk + i * 16 + l16) * IN_DIM + s * 32 + quad * 8);
    stage_write(WB[0], wid, lane, st);
    __syncthreads();

    const __bf16* wp = Wp;    // current group base (4096 elems = 8KB per group)

    // ---- layer 1: groups 0..7 (group j in WB[j&1]) ----
    #pragma unroll 1
    for (int j = 0; j < 8; ++j) {
        stage_issue(wp + 4096, wid, lane, st);
        read_frags(WB[j & 1], lane, f);
        float bt0 = b1[j * 32 + l16];
        float bt1 = b1[j * 32 + 16 + l16];
        f32x4 acc[4][2] = {};
        mfma_L1(a, f, acc);
        store_H(Hw, j, quad, l16, acc, bt0, bt1);
        stage_write(WB[(j + 1) & 1], wid, lane, st);
        __syncthreads();
        wp += 4096;
    }
    // wp = group 8 (resident in WB[0])

    // ---- layer 2 A-frags from LDS ----
    #pragma unroll
    for (int i = 0; i < 4; ++i)
        #pragma unroll
        for (int s = 0; s < 8; ++s) {
            int row = i * 16 + l16;
            a[i][s] = *(const bf16x8*)(Hw + row * 256 + (((s * 4 + quad) + row) & 31) * 8);
        }

    // ---- layer 2: groups 8..23 (slab j = even group t0 + odd group t1) ----
    #pragma unroll 1
    for (int j = 0; j < 8; ++j) {
        f32x4 acc[4][2] = {};
        // even group (parity 0 -> WB[0])
        stage_issue(wp + 4096, wid, lane, st);
        read_frags(WB[0], lane, f);
        mfma_K256(a, f, acc, 0);
        stage_write(WB[1], wid, lane, st);
        __syncthreads();
        wp += 4096;
        // odd group (parity 1 -> WB[1])
        stage_issue(wp + 4096, wid, lane, st);
        read_frags(WB[1], lane, f);
        mfma_K256(a, f, acc, 1);
        stage_write(WB[0], wid, lane, st);
        __syncthreads();
        wp += 4096;
        float bt0 = b2[j * 32 + l16];
        float bt1 = b2[j * 32 + 16 + l16];
        store_H(Hw, j, quad, l16, acc, bt0, bt1);
    }
    // wp = group 24 (resident in WB[0])

    // ---- layer 3 A-frags from LDS ----
    #pragma unroll
    for (int i = 0; i < 4; ++i)
        #pragma unroll
        for (int s = 0; s < 8; ++s) {
            int row = i * 16 + l16;
            a[i][s] = *(const bf16x8*)(Hw + row * 256 + (((s * 4 + quad) + row) & 31) * 8);
        }

    // ---- layer 3: groups 24..31 (4 slabs), pooled atomic output ----
    #pragma unroll 1
    for (int j = 0; j < 4; ++j) {
        f32x4 acc[4][2] = {};
        // even group
        stage_issue(wp + 4096, wid, lane, st);
        read_frags(WB[0], lane, f);
        mfma_K256(a, f, acc, 0);
        stage_write(WB[1], wid, lane, st);
        __syncthreads();
        wp += 4096;
        // odd group (last iter stages past Wp into pairBuf — harmless)
        stage_issue(wp + 4096, wid, lane, st);
        read_frags(WB[1], lane, f);
        mfma_K256(a, f, acc, 1);
        stage_write(WB[0], wid, lane, st);
        __syncthreads();
        wp += 4096;
        float bt0 = bo[j * 32 + l16];
        float bt1 = bo[j * 32 + 16 + l16];

        if (gfirst == glast) {
            #pragma unroll
            for (int t = 0; t < 2; ++t) {
                float sum = 0.f;
                #pragma unroll
                for (int i = 0; i < 4; ++i)
                    #pragma unroll
                    for (int rr = 0; rr < 4; ++rr) sum += acc[i][t][rr];
                sum += __shfl_xor(sum, 16, 64);
                sum += __shfl_xor(sum, 32, 64);
                if (quad == 0) {
                    int c = j * 32 + t * 16 + l16;
                    float bb = t ? bt1 : bt0;
                    atomicAdd(out + (size_t)gfirst * OUT_DIM + c, sum + 64.f * bb);
                }
            }
        } else {
            #pragma unroll
            for (int i = 0; i < 4; ++i)
                #pragma unroll
                for (int rr = 0; rr < 4; ++rr) {
                    int m = r0g + i * 16 + quad * 4 + rr;
                    if (m < N_NODES) {
                        int g = batch[m];
                        #pragma unroll
                        for (int t = 0; t < 2; ++t) {
                            int c = j * 32 + t * 16 + l16;
                            float bb = t ? bt1 : bt0;
                            atomicAdd(out + (size_t)g * OUT_DIM + c, acc[i][t][rr] + bb);
                        }
                    }
                }
        }
    }
}

extern "C" void kernel_launch(void* const* d_in, const int* in_sizes, int n_in,
                              void* d_out, int out_size, void* d_ws, size_t ws_size,
                              hipStream_t stream) {
    const float* x  = (const float*)d_in[0];
    const int*   ei = (const int*)d_in[1];
    const int*   bi = (const int*)d_in[2];
    const float* W1 = (const float*)d_in[3];
    const float* b1 = (const float*)d_in[4];
    const float* W2 = (const float*)d_in[5];
    const float* b2 = (const float*)d_in[6];
    const float* Wo = (const float*)d_in[7];
    const float* bo = (const float*)d_in[8];
    float* out = (float*)d_out;

    __bf16* A  = (__bf16*)d_ws;                        // [M_PAD][128]
    __bf16* xb = A + (size_t)M_PAD * IN_DIM;           // [N_NODES][128]
    __bf16* Wp = xb + (size_t)N_NODES * IN_DIM;        // [131072] packed frag-ordered
    unsigned* pairBuf = (unsigned*)(Wp + WP_TOTAL);    // [NB*BCAP]
    int* nbr      = (int*)(pairBuf + (size_t)NB * BCAP);
    int* offsets  = nbr + (size_t)NB * BCAP;
    int* deg      = offsets + N_NODES;
    int* gcursor  = deg + N_NODES;

    // ---- fused init ----
    init_kernel<<<(R_TOTAL + 255) / 256, 256, 0, stream>>>(
        x, W1, W2, Wo, xb, A + (size_t)N_NODES * IN_DIM, Wp, out, gcursor);

    // ---- CSR build ----
    bucket_v2_kernel<<<BKB, 256, 0, stream>>>(ei, gcursor, pairBuf);
    passB_kernel<<<NB, 256, 0, stream>>>(pairBuf, gcursor, nbr, offsets, deg);

    // ---- aggregate ----
    aggregate_kernel<<<(N_NODES + 3) / 4, 256, 0, stream>>>(xb, offsets, deg, nbr, A);

    // ---- fused MLP + pool (2-wave blocks, 64-row waves, LDS weight dbuf) ----
    mlp_fused<<<M_PAD / MLP_ROWS_B, MLP_WAVES * 64, 0, stream>>>(A, Wp, b1, b2, bo, out, bi);
}

// Round 3
// 298.335 us; speedup vs baseline: 1.1281x; 1.1281x over previous
//
#include <hip/hip_runtime.h>

#define N_NODES  100000
#define M_PAD    100096   // 782 * 128 (and 3128 * 32)
#define N_EDGES  1600000
#define N_GRAPHS 512
#define IN_DIM   128
#define HID_DIM  256
#define OUT_DIM  128

#define NB       782      // buckets of 128 nodes
#define BCAP     3072     // mean 2048, +22 sigma headroom
#define CHUNK    2048     // edges per bucket_v2 block
#define BKB      ((N_EDGES + CHUNK - 1) / CHUNK)   // 782

typedef __bf16 bf16x8 __attribute__((ext_vector_type(8)));
typedef __bf16 bf16x4 __attribute__((ext_vector_type(4)));
typedef __bf16 bf16x2 __attribute__((ext_vector_type(2)));
typedef float  f32x4  __attribute__((ext_vector_type(4)));

// ---- packed weight buffer layout (frag-ordered, LINEAR group stream) ----
// 32 groups x 8 frags x 512 elems: L1 groups 0-7, L2 8-23, L3 24-31.
#define WP_L2_BASE 32768
#define WP_L3_BASE 98304
#define WP_TOTAL   131072

// ---------------- fused init ----------------
#define R_X    (N_NODES * IN_DIM / 4)
#define R_APAD ((M_PAD - N_NODES) * IN_DIM / 4)
#define R_WP   WP_TOTAL
#define R_OUT  (N_GRAPHS * OUT_DIM / 4)
#define R_CUR  NB
#define R_TOTAL (R_X + R_APAD + R_WP + R_OUT + R_CUR)

__global__ __launch_bounds__(256) void init_kernel(const float* __restrict__ x,
                                                   const float* __restrict__ W1,
                                                   const float* __restrict__ W2,
                                                   const float* __restrict__ Wo,
                                                   __bf16* __restrict__ xb,
                                                   __bf16* __restrict__ Apad,
                                                   __bf16* __restrict__ Wp,
                                                   float* __restrict__ outbuf,
                                                   int* __restrict__ gcursor) {
    long long i = (long long)blockIdx.x * blockDim.x + threadIdx.x;
    if (i < R_X) {
        float4 v = ((const float4*)x)[i];
        bf16x4 h;
        h.x = (__bf16)v.x; h.y = (__bf16)v.y; h.z = (__bf16)v.z; h.w = (__bf16)v.w;
        ((bf16x4*)xb)[i] = h;
        return;
    }
    i -= R_X;
    if (i < R_APAD) {
        bf16x4 z; z.x = (__bf16)0.f; z.y = (__bf16)0.f; z.z = (__bf16)0.f; z.w = (__bf16)0.f;
        ((bf16x4*)Apad)[i] = z;
        return;
    }
    i -= R_APAD;
    if (i < R_WP) {
        int idx = (int)i;
        const float* src;
        int K, Nn, base;
        if (idx < WP_L2_BASE)      { src = W1; K = 128; Nn = 256; base = 0; }
        else if (idx < WP_L3_BASE) { src = W2; K = 256; Nn = 256; base = WP_L2_BASE; }
        else                       { src = Wo; K = 256; Nn = 128; base = WP_L3_BASE; }
        int r0 = idx - base;
        int slabElems = 32 * K;          // power of two
        int j = r0 / slabElems;
        int r = r0 % slabElems;
        int KS = K / 32;
        int p = r >> 9;
        int lane = (r >> 3) & 63;
        int e = r & 7;
        int s = p % KS, t = p / KS;
        int quad = lane >> 4, l16 = lane & 15;
        int n = j * 32 + t * 16 + l16;
        int k = s * 32 + quad * 8 + e;
        Wp[idx] = (__bf16)src[(size_t)k * Nn + n];
        return;
    }
    i -= R_WP;
    if (i < R_OUT) {
        ((float4*)outbuf)[i] = make_float4(0.f, 0.f, 0.f, 0.f);
        return;
    }
    i -= R_OUT;
    if (i < R_CUR) gcursor[i] = 0;
}

// ---------------- bucket_v2: LDS-staged edge binning ----------------
__global__ __launch_bounds__(256) void bucket_v2_kernel(const int* __restrict__ ei,
                                                        int* __restrict__ gcursor,
                                                        unsigned* __restrict__ pairBuf) {
    __shared__ int lcnt[NB];
    __shared__ int lbase[NB];
    const int tid = threadIdx.x;
    const int e0 = blockIdx.x * CHUNK;

    for (int b = tid; b < NB; b += 256) lcnt[b] = 0;
    __syncthreads();

    for (int i = tid; i < CHUNK; i += 256) {
        int e = e0 + i;
        if (e < N_EDGES) atomicAdd(&lcnt[ei[N_EDGES + e] >> 7], 1);
    }
    __syncthreads();

    for (int b = tid; b < NB; b += 256) {
        int c = lcnt[b];
        lbase[b] = c ? atomicAdd(&gcursor[b], c) : 0;
        lcnt[b] = 0;
    }
    __syncthreads();

    for (int i = tid; i < CHUNK; i += 256) {
        int e = e0 + i;
        if (e < N_EDGES) {
            int s = ei[e];
            int d = ei[N_EDGES + e];
            int b = d >> 7;
            int pos = lbase[b] + atomicAdd(&lcnt[b], 1);
            if (pos < BCAP)
                pairBuf[(size_t)b * BCAP + pos] = (unsigned)s | ((unsigned)(d & 127) << 17);
        }
    }
}

// ---------------- passB: per-bucket CSR build (bucket-strided) ----------------
__global__ __launch_bounds__(256) void passB_kernel(const unsigned* __restrict__ pairBuf,
                                                    const int* __restrict__ gcursor,
                                                    int* __restrict__ nbr,
                                                    int* __restrict__ offsets,
                                                    int* __restrict__ deg) {
    __shared__ int lcnt[128];
    __shared__ int loffs[128];
    __shared__ int lcur[128];
    const int b = blockIdx.x;
    const int tid = threadIdx.x;
    const int node0 = b << 7;
    const int cnt = min(gcursor[b], BCAP);
    const int base = b * BCAP;
    const unsigned* pb = pairBuf + (size_t)b * BCAP;

    if (tid < 128) { lcnt[tid] = 0; lcur[tid] = 0; }
    __syncthreads();

    for (int i = tid; i < cnt; i += 256)
        atomicAdd(&lcnt[pb[i] >> 17], 1);
    __syncthreads();

    if (tid < 128) loffs[tid] = lcnt[tid];
    __syncthreads();
    for (int st = 1; st < 128; st <<= 1) {
        int add = (tid < 128 && tid >= st) ? loffs[tid - st] : 0;
        __syncthreads();
        if (tid < 128) loffs[tid] += add;
        __syncthreads();
    }
    int excl = 0;
    if (tid < 128) {
        excl = loffs[tid] - lcnt[tid];
        int node = node0 + tid;
        if (node < N_NODES) {
            deg[node] = lcnt[tid];
            offsets[node] = base + excl;
        }
    }
    __syncthreads();
    if (tid < 128) loffs[tid] = excl;
    __syncthreads();

    for (int i = tid; i < cnt; i += 256) {
        unsigned u = pb[i];
        int dl = u >> 17;
        int slot = atomicAdd(&lcur[dl], 1);
        nbr[base + loffs[dl] + slot] = (int)(u & 0x1FFFF);
    }
}

// ---------------- gather aggregate (at memory floor) ----------------
__global__ __launch_bounds__(256) void aggregate_kernel(const __bf16* __restrict__ xb,
                                                        const int* __restrict__ offsets,
                                                        const int* __restrict__ deg,
                                                        const int* __restrict__ nbr,
                                                        __bf16* __restrict__ A) {
    int v = blockIdx.x * 4 + (threadIdx.x >> 6);
    v = __builtin_amdgcn_readfirstlane(v);
    int lane = threadIdx.x & 63;
    if (v >= N_NODES) return;
    int off = offsets[v];
    int len = deg[v];
    const int c0 = lane * 2;
    bf16x2 self = *(const bf16x2*)(xb + (size_t)v * IN_DIM + c0);
    float ax = (float)self.x, ay = (float)self.y;

    int addr = off + lane;
    if (addr > NB * BCAP - 1) addr = NB * BCAP - 1;
    int myidx = nbr[addr];

    int lim = len < 64 ? len : 64;
    int j = 0;
    for (; j + 8 <= lim; j += 8) {
        int s0 = __shfl(myidx, j + 0, 64);
        int s1 = __shfl(myidx, j + 1, 64);
        int s2 = __shfl(myidx, j + 2, 64);
        int s3 = __shfl(myidx, j + 3, 64);
        int s4 = __shfl(myidx, j + 4, 64);
        int s5 = __shfl(myidx, j + 5, 64);
        int s6 = __shfl(myidx, j + 6, 64);
        int s7 = __shfl(myidx, j + 7, 64);
        bf16x2 v0 = *(const bf16x2*)(xb + (size_t)s0 * IN_DIM + c0);
        bf16x2 v1 = *(const bf16x2*)(xb + (size_t)s1 * IN_DIM + c0);
        bf16x2 v2 = *(const bf16x2*)(xb + (size_t)s2 * IN_DIM + c0);
        bf16x2 v3 = *(const bf16x2*)(xb + (size_t)s3 * IN_DIM + c0);
        bf16x2 v4 = *(const bf16x2*)(xb + (size_t)s4 * IN_DIM + c0);
        bf16x2 v5 = *(const bf16x2*)(xb + (size_t)s5 * IN_DIM + c0);
        bf16x2 v6 = *(const bf16x2*)(xb + (size_t)s6 * IN_DIM + c0);
        bf16x2 v7 = *(const bf16x2*)(xb + (size_t)s7 * IN_DIM + c0);
        ax += (float)v0.x + (float)v1.x + (float)v2.x + (float)v3.x
            + (float)v4.x + (float)v5.x + (float)v6.x + (float)v7.x;
        ay += (float)v0.y + (float)v1.y + (float)v2.y + (float)v3.y
            + (float)v4.y + (float)v5.y + (float)v6.y + (float)v7.y;
    }
    for (; j < lim; ++j) {
        int s = __shfl(myidx, j, 64);
        bf16x2 vv = *(const bf16x2*)(xb + (size_t)s * IN_DIM + c0);
        ax += (float)vv.x;
        ay += (float)vv.y;
    }
    for (; j < len; ++j) {
        int s = nbr[off + j];
        bf16x2 vv = *(const bf16x2*)(xb + (size_t)s * IN_DIM + c0);
        ax += (float)vv.x;
        ay += (float)vv.y;
    }
    bf16x2 h;
    h.x = (__bf16)ax;
    h.y = (__bf16)ay;
    *(bf16x2*)(A + (size_t)v * IN_DIM + c0) = h;
}

// ---------------- fused 3-layer MLP + pool ----------------
// v4: v2 structure (32-row waves, wave-private reg weight stream) + three fixes:
//  1. 4-wave blocks (H = 64KB -> exactly 2 blocks/CU; launch_bounds(256,2)
//     caps VGPR at 256 -> 8 waves/CU guaranteed; v2 measured only ~4).
//  2. Depth-2 weight prefetch via 4 rotating reg buffers (static indexing):
//     every group's loads are issued >= 1 full slab (~600cy) before first
//     MFMA use. v2's in-slab odd group had only ~80cy distance -> exposed
//     ~200cy L2 stall per slab.
//  3. All 4 waves read the SAME weight addresses concurrently -> L1 hits for
//     3 of 4 (group 8KB, L1 32KB); per-layer barrier keeps streams cohesive.
// No per-group barriers, no LDS weight staging (v3's failure mode).
#define MLP_WAVES   4
#define MLP_ROWS_W  32
#define MLP_ROWS_B  (MLP_WAVES * MLP_ROWS_W)   // 128

__device__ __forceinline__ void load_group4(const __bf16* __restrict__ p, int lane,
                                            bf16x8* __restrict__ dst) {
    #pragma unroll
    for (int e = 0; e < 8; ++e)
        dst[e] = *(const bf16x8*)(p + (e * 64 + lane) * 8);
}

__device__ __forceinline__ void store_H(__bf16* __restrict__ H, int j, int quad, int l16,
                                        const f32x4 (&acc)[2][2], float bt0, float bt1) {
    const int c7 = l16 & 7;
    const int ch = l16 >> 3;
    #pragma unroll
    for (int i = 0; i < 2; ++i)
        #pragma unroll
        for (int t = 0; t < 2; ++t) {
            const float bb = t ? bt1 : bt0;
            #pragma unroll
            for (int rr = 0; rr < 4; ++rr) {
                int row = i * 16 + quad * 4 + rr;
                int cidx = (j * 4 + t * 2 + ch + row) & 31;
                float v = fmaxf(acc[i][t][rr] + bb, 0.f);
                H[row * 256 + cidx * 8 + c7] = (__bf16)v;
            }
        }
}

__global__ __launch_bounds__(256, 2) void mlp_fused(const __bf16* __restrict__ A,
                                                    const __bf16* __restrict__ Wp,
                                                    const float* __restrict__ b1,
                                                    const float* __restrict__ b2,
                                                    const float* __restrict__ bo,
                                                    float* __restrict__ out,
                                                    const int* __restrict__ batch) {
    __shared__ __align__(16) __bf16 H[MLP_WAVES][32 * 256];   // 64 KB

    const int tid  = threadIdx.x;
    const int wid  = tid >> 6;
    const int lane = tid & 63;
    const int quad = lane >> 4, l16 = lane & 15;
    __bf16* Hw = H[wid];

    const size_t mblk = (size_t)blockIdx.x * MLP_ROWS_B + wid * MLP_ROWS_W;
    const int r0g = (int)mblk;
    int gfirst = (r0g < N_NODES) ? batch[r0g] : -2;
    int glast  = (r0g + 31 < N_NODES) ? batch[r0g + 31] : -1;

    bf16x8 a[2][8];
    bf16x8 w0[8], w1[8], w2[8], w3[8];

    // ---- prologue: groups 0,1 in flight + layer-1 A-frags ----
    load_group4(Wp, lane, w0);
    load_group4(Wp + 4096, lane, w1);
    #pragma unroll
    for (int i = 0; i < 2; ++i)
        #pragma unroll
        for (int s = 0; s < 4; ++s)
            a[i][s] = *(const bf16x8*)(A + (mblk + i * 16 + l16) * IN_DIM + s * 32 + quad * 8);

    // ---- layer 1: groups 0..7 (group j = one 32-col slab, KS=4) ----
#define L1_BODY(J, CW, PW)                                                              \
    {                                                                                   \
        load_group4(Wp + (size_t)((J) + 2) * 4096, lane, PW);                           \
        float bt0 = b1[(J) * 32 + l16];                                                 \
        float bt1 = b1[(J) * 32 + 16 + l16];                                            \
        f32x4 acc[2][2] = {};                                                           \
        _Pragma("unroll")                                                               \
        for (int p = 0; p < 8; ++p) {                                                   \
            const int t = p >> 2, s = p & 3;                                            \
            acc[0][t] = __builtin_amdgcn_mfma_f32_16x16x32_bf16(a[0][s], CW[p], acc[0][t], 0, 0, 0); \
            acc[1][t] = __builtin_amdgcn_mfma_f32_16x16x32_bf16(a[1][s], CW[p], acc[1][t], 0, 0, 0); \
        }                                                                               \
        store_H(Hw, (J), quad, l16, acc, bt0, bt1);                                     \
    }

    #pragma unroll 1
    for (int j = 0; j < 8; j += 4) {
        L1_BODY(j + 0, w0, w2)
        L1_BODY(j + 1, w1, w3)
        L1_BODY(j + 2, w2, w0)
        L1_BODY(j + 3, w3, w1)
    }
#undef L1_BODY
    // w0 = g8, w1 = g9 in flight
    __syncthreads();

    // ---- layer 2 A-frags from LDS ----
    #pragma unroll
    for (int i = 0; i < 2; ++i)
        #pragma unroll
        for (int s = 0; s < 8; ++s) {
            int row = i * 16 + l16;
            a[i][s] = *(const bf16x8*)(Hw + row * 256 + (((s * 4 + quad) + row) & 31) * 8);
        }

    // slab body for K=256 layers: consumes groups (GB+2j, GB+2j+1), prefetches next 2
#define K256_BODY(GB, J, CE, CO, PE, PO, BIAS, TAIL)                                    \
    {                                                                                   \
        const __bf16* pf = Wp + (size_t)((GB) + 2 * (J) + 2) * 4096;                    \
        load_group4(pf, lane, PE);                                                      \
        load_group4(pf + 4096, lane, PO);                                               \
        float bt0 = BIAS[(J) * 32 + l16];                                               \
        float bt1 = BIAS[(J) * 32 + 16 + l16];                                          \
        f32x4 acc[2][2] = {};                                                           \
        _Pragma("unroll")                                                               \
        for (int p = 0; p < 8; ++p) {                                                   \
            acc[0][0] = __builtin_amdgcn_mfma_f32_16x16x32_bf16(a[0][p], CE[p], acc[0][0], 0, 0, 0); \
            acc[1][0] = __builtin_amdgcn_mfma_f32_16x16x32_bf16(a[1][p], CE[p], acc[1][0], 0, 0, 0); \
        }                                                                               \
        _Pragma("unroll")                                                               \
        for (int p = 0; p < 8; ++p) {                                                   \
            acc[0][1] = __builtin_amdgcn_mfma_f32_16x16x32_bf16(a[0][p], CO[p], acc[0][1], 0, 0, 0); \
            acc[1][1] = __builtin_amdgcn_mfma_f32_16x16x32_bf16(a[1][p], CO[p], acc[1][1], 0, 0, 0); \
        }                                                                               \
        TAIL                                                                            \
    }

    // ---- layer 2: groups 8..23, slabs 0..7 ----
    #pragma unroll 1
    for (int j = 0; j < 8; j += 2) {
        K256_BODY(8, j,     w0, w1, w2, w3, b2, store_H(Hw, j,     quad, l16, acc, bt0, bt1);)
        K256_BODY(8, j + 1, w2, w3, w0, w1, b2, store_H(Hw, j + 1, quad, l16, acc, bt0, bt1);)
    }
    // w0 = g24, w1 = g25 in flight
    __syncthreads();

    // ---- layer 3 A-frags from LDS ----
    #pragma unroll
    for (int i = 0; i < 2; ++i)
        #pragma unroll
        for (int s = 0; s < 8; ++s) {
            int row = i * 16 + l16;
            a[i][s] = *(const bf16x8*)(Hw + row * 256 + (((s * 4 + quad) + row) & 31) * 8);
        }

#define L3_TAIL(J)                                                                      \
    if (gfirst == glast) {                                                              \
        _Pragma("unroll")                                                               \
        for (int t = 0; t < 2; ++t) {                                                   \
            float sum = 0.f;                                                            \
            _Pragma("unroll")                                                           \
            for (int i = 0; i < 2; ++i)                                                 \
                _Pragma("unroll")                                                       \
                for (int rr = 0; rr < 4; ++rr) sum += acc[i][t][rr];                    \
            sum += __shfl_xor(sum, 16, 64);                                             \
            sum += __shfl_xor(sum, 32, 64);                                             \
            if (quad == 0) {                                                            \
                int c = (J) * 32 + t * 16 + l16;                                        \
                float bb = t ? bt1 : bt0;                                               \
                atomicAdd(out + (size_t)gfirst * OUT_DIM + c, sum + 32.f * bb);         \
            }                                                                           \
        }                                                                               \
    } else {                                                                            \
        _Pragma("unroll")                                                               \
        for (int i = 0; i < 2; ++i)                                                     \
            _Pragma("unroll")                                                           \
            for (int rr = 0; rr < 4; ++rr) {                                            \
                int m = r0g + i * 16 + quad * 4 + rr;                                   \
                if (m < N_NODES) {                                                      \
                    int g = batch[m];                                                   \
                    _Pragma("unroll")                                                   \
                    for (int t = 0; t < 2; ++t) {                                       \
                        int c = (J) * 32 + t * 16 + l16;                                \
                        float bb = t ? bt1 : bt0;                                       \
                        atomicAdd(out + (size_t)g * OUT_DIM + c, acc[i][t][rr] + bb);   \
                    }                                                                   \
                }                                                                       \
            }                                                                           \
    }

    // ---- layer 3: groups 24..31, slabs 0..3 (last prefetch reads past Wp into pairBuf — harmless) ----
    #pragma unroll 1
    for (int j = 0; j < 4; j += 2) {
        K256_BODY(24, j,     w0, w1, w2, w3, bo, L3_TAIL(j))
        K256_BODY(24, j + 1, w2, w3, w0, w1, bo, L3_TAIL(j + 1))
    }
#undef K256_BODY
#undef L3_TAIL
}

extern "C" void kernel_launch(void* const* d_in, const int* in_sizes, int n_in,
                              void* d_out, int out_size, void* d_ws, size_t ws_size,
                              hipStream_t stream) {
    const float* x  = (const float*)d_in[0];
    const int*   ei = (const int*)d_in[1];
    const int*   bi = (const int*)d_in[2];
    const float* W1 = (const float*)d_in[3];
    const float* b1 = (const float*)d_in[4];
    const float* W2 = (const float*)d_in[5];
    const float* b2 = (const float*)d_in[6];
    const float* Wo = (const float*)d_in[7];
    const float* bo = (const float*)d_in[8];
    float* out = (float*)d_out;

    __bf16* A  = (__bf16*)d_ws;                        // [M_PAD][128]
    __bf16* xb = A + (size_t)M_PAD * IN_DIM;           // [N_NODES][128]
    __bf16* Wp = xb + (size_t)N_NODES * IN_DIM;        // [131072] packed frag-ordered
    unsigned* pairBuf = (unsigned*)(Wp + WP_TOTAL);    // [NB*BCAP]
    int* nbr      = (int*)(pairBuf + (size_t)NB * BCAP);
    int* offsets  = nbr + (size_t)NB * BCAP;
    int* deg      = offsets + N_NODES;
    int* gcursor  = deg + N_NODES;

    // ---- fused init ----
    init_kernel<<<(R_TOTAL + 255) / 256, 256, 0, stream>>>(
        x, W1, W2, Wo, xb, A + (size_t)N_NODES * IN_DIM, Wp, out, gcursor);

    // ---- CSR build ----
    bucket_v2_kernel<<<BKB, 256, 0, stream>>>(ei, gcursor, pairBuf);
    passB_kernel<<<NB, 256, 0, stream>>>(pairBuf, gcursor, nbr, offsets, deg);

    // ---- aggregate ----
    aggregate_kernel<<<(N_NODES + 3) / 4, 256, 0, stream>>>(xb, offsets, deg, nbr, A);

    // ---- fused MLP + pool (4-wave blocks, 32-row waves, depth-2 reg prefetch) ----
    mlp_fused<<<M_PAD / MLP_ROWS_B, MLP_WAVES * 64, 0, stream>>>(A, Wp, b1, b2, bo, out, bi);
}